// Round 3
// baseline (445.745 us; speedup 1.0000x reference)
//
#include <hip/hip_runtime.h>

// MoE EP-combine: out[idx[r]] += gates[r] * expert[r]   (fp32)
// Gather formulation: CSR-lite build in d_ws (counts + fixed-width slot
// lists), then ONE WAVE PER TOKEN streams each contributor row as a full
// 8KB sequential burst (8 independent 1KB float4 loads in flight), weights,
// sums, writes the output row once (no pre-zero of d_out needed).
//
// History: round-1 proved the 2x1GiB 0xAA ws re-poison fills (~326us/iter)
// are UNCONDITIONAL (ws-free variant still showed them). Round-2 proved the
// contributor-loop unroll-2 is neutral -> combine is not MLP-starved at the
// 2-blocks/token 4KB-granule structure; it runs ~95us for a 402MB payload
// (~4.3 TB/s) vs harness fills at 6.58 TB/s. This round: raise HBM gather
// efficiency via 8KB-sequential-per-wave reads + 8-deep MLP + 1x (not 2x)
// counts/slots/gates overhead. VGPR ~90 -> 4 waves/SIMD (16/CU), 128KB
// outstanding per CU >> ~10KB needed to sustain BW.

static constexpr int NT   = 256;  // threads per block (4 waves -> 4 tokens)
static constexpr int MAXK = 32;   // max contributors per token (Poisson(2) max ~13)

typedef float fvec4 __attribute__((ext_vector_type(4)));

__device__ __forceinline__ void fma4(fvec4& a, float g, fvec4 e) {
    a.x = fmaf(g, e.x, a.x);
    a.y = fmaf(g, e.y, a.y);
    a.z = fmaf(g, e.z, a.z);
    a.w = fmaf(g, e.w, a.w);
}

// Inline int64-layout detection: if the index buffer is int64 (little-endian),
// the high 32-bit words of the first 16 values are all zero (indices small,
// non-negative). For int32 data those words are 16 independent token indices —
// all-zero with probability ~16384^-16. Wave-uniform reads -> L1 broadcast.
__device__ __forceinline__ int detect_is64(const int* __restrict__ idx32) {
    int is64 = 1;
#pragma unroll
    for (int i = 1; i < 32; i += 2) is64 &= (idx32[i] == 0);
    return is64;
}

__global__ void fill_kernel(const int* __restrict__ idx32,
                            const long long* __restrict__ idx64,
                            int* __restrict__ counts,
                            int* __restrict__ slots,
                            int num_sel, int num_tokens) {
    int r = blockIdx.x * blockDim.x + threadIdx.x;
    if (r >= num_sel) return;
    int is64 = detect_is64(idx32);
    int t = is64 ? (int)idx64[r] : idx32[r];
    if ((unsigned)t >= (unsigned)num_tokens) return;  // safety net
    int j = atomicAdd(&counts[t], 1);
    if (j < MAXK) slots[t * MAXK + j] = r;
}

// d_model == 2048: one wave per token. Lane l, chunk k covers float4 index
// (l + 64k), k=0..7 -> the wave reads/writes the full 8KB row as 8 contiguous
// 1KB vector-load instructions, all independent (8-deep MLP per row).
__global__ __launch_bounds__(NT) void combine2048_wave_kernel(
    const float* __restrict__ expert,
    const float* __restrict__ gates,
    const int* __restrict__ counts,
    const int* __restrict__ slots,
    float* __restrict__ out,
    int num_tokens) {
    const int lane = threadIdx.x & 63;
    const int t    = blockIdx.x * (NT / 64) + (threadIdx.x >> 6);  // token
    if (t >= num_tokens) return;
    int c = counts[t];
    if (c > MAXK) c = MAXK;
    const int* sl = slots + (size_t)t * MAXK;

    fvec4 acc[8];
#pragma unroll
    for (int k = 0; k < 8; ++k) acc[k] = (fvec4)(0.f);

    for (int j = 0; j < c; ++j) {
        const int   r = sl[j];        // wave-uniform -> s_load, L2-hot
        const float g = gates[r];     // wave-uniform, L2-hot
        const fvec4* R = (const fvec4*)(expert + (size_t)r * 2048) + lane;
        fvec4 e[8];
#pragma unroll
        for (int k = 0; k < 8; ++k)
            e[k] = __builtin_nontemporal_load(R + (size_t)k * 64);  // streamed once
#pragma unroll
        for (int k = 0; k < 8; ++k)
            fma4(acc[k], g, e[k]);
    }

    fvec4* O = (fvec4*)(out + (size_t)t * 2048) + lane;
#pragma unroll
    for (int k = 0; k < 8; ++k)
        __builtin_nontemporal_store(acc[k], O + (size_t)k * 64);  // write-only: nt
}

// Fallback: plain atomic scatter (generic d_model, or ws too small).
__global__ void scatter_atomic_kernel(const float* __restrict__ expert,
                                      const float* __restrict__ gates,
                                      const int* __restrict__ idx32,
                                      const long long* __restrict__ idx64,
                                      float* __restrict__ out,
                                      int d_model, int num_tokens) {
    int r = blockIdx.x;
    int is64 = detect_is64(idx32);
    int t = is64 ? (int)idx64[r] : idx32[r];
    if ((unsigned)t >= (unsigned)num_tokens) return;
    float g = gates[r];
    const float* row  = expert + (size_t)r * d_model;
    float*       orow = out    + (size_t)t * d_model;
    for (int v = threadIdx.x; v < d_model; v += blockDim.x)
        atomicAdd(&orow[v], g * row[v]);
}

extern "C" void kernel_launch(void* const* d_in, const int* in_sizes, int n_in,
                              void* d_out, int out_size, void* d_ws, size_t ws_size,
                              hipStream_t stream) {
    const float*      expert = (const float*)d_in[1];
    const float*      gates  = (const float*)d_in[2];
    const int*        idx32  = (const int*)d_in[3];
    const long long*  idx64  = (const long long*)d_in[3];
    float*            out    = (float*)d_out;

    const int num_sel    = in_sizes[2];
    const int d_model    = (int)((long long)in_sizes[1] / num_sel);
    const int num_tokens = (int)((long long)out_size / d_model);

    int*  counts = (int*)d_ws;
    int*  slots  = (int*)((char*)d_ws + (size_t)num_tokens * 4);
    const size_t need = (size_t)num_tokens * 4 + (size_t)num_tokens * MAXK * 4;

    if (d_model == 2048 && ws_size >= need) {
        (void)hipMemsetAsync(counts, 0, (size_t)num_tokens * 4, stream);
        fill_kernel<<<(num_sel + NT - 1) / NT, NT, 0, stream>>>(
            idx32, idx64, counts, slots, num_sel, num_tokens);
        const int tokens_per_block = NT / 64;
        combine2048_wave_kernel<<<(num_tokens + tokens_per_block - 1) / tokens_per_block,
                                  NT, 0, stream>>>(
            expert, gates, counts, slots, out, num_tokens);
    } else {
        (void)hipMemsetAsync(d_out, 0, (size_t)out_size * sizeof(float), stream);
        scatter_atomic_kernel<<<num_sel, NT, 0, stream>>>(
            expert, gates, idx32, idx64, out, d_model, num_tokens);
    }
}